// Round 2
// baseline (738.429 us; speedup 1.0000x reference)
//
#include <hip/hip_runtime.h>

typedef __bf16 bf8 __attribute__((ext_vector_type(8)));
typedef float f4 __attribute__((ext_vector_type(4)));

__device__ __forceinline__ float b2f(unsigned short u) {
  union { unsigned int i; float f; } c; c.i = ((unsigned int)u) << 16; return c.f;
}
__device__ __forceinline__ unsigned short f2b(float f) {
  union { float f; unsigned int i; } c; c.f = f;
  unsigned int i = c.i;
  return (unsigned short)((i + 0x7FFFu + ((i >> 16) & 1u)) >> 16);  // RNE
}

// ---------------- weight transpose+cast: f32 [K,N] -> bf16 [N,K] ----------------
__global__ void transpose_kernel(const float* __restrict__ in,
                                 unsigned short* __restrict__ out, int K, int N) {
  int idx = blockIdx.x * 256 + threadIdx.x;
  if (idx < K * N) {
    int n = idx / K, k = idx - n * K;
    out[idx] = f2b(in[k * N + n]);
  }
}

// ---------------- LayerNorm: C=192, one wave per token, f32 in -> bf16 out ----------------
__global__ __launch_bounds__(256) void ln_kernel(const float* __restrict__ xin,
                                                 const float* __restrict__ g,
                                                 const float* __restrict__ bb,
                                                 unsigned short* __restrict__ out) {
  long token = (long)blockIdx.x * 4 + (threadIdx.x >> 6);
  int lane = threadIdx.x & 63;
  const float* row = xin + token * 192;
  float v[3] = {row[lane], row[lane + 64], row[lane + 128]};
  float s = v[0] + v[1] + v[2];
#pragma unroll
  for (int m = 1; m < 64; m <<= 1) s += __shfl_xor(s, m, 64);
  float mean = s * (1.0f / 192.0f);
  float d0 = v[0] - mean, d1 = v[1] - mean, d2 = v[2] - mean;
  float dd = d0 * d0 + d1 * d1 + d2 * d2;
#pragma unroll
  for (int m = 1; m < 64; m <<= 1) dd += __shfl_xor(dd, m, 64);
  float rstd = rsqrtf(dd * (1.0f / 192.0f) + 1e-5f);
  unsigned short* orow = out + token * 192;
#pragma unroll
  for (int i = 0; i < 3; i++) {
    int c = lane + i * 64;
    orow[c] = f2b((v[i] - mean) * rstd * g[c] + bb[c]);
  }
}

// ---------------- MFMA GEMM: out = A[M,K](bf16) @ Bt[N,K]^T(bf16) + bias(f32) ----------------
// EPI 0: out bf16 = v                        (qkv)
// EPI 1: out f32  = v + f32 residual         (proj + shortcut)
// EPI 2: out bf16 = gelu(v) exact erf        (fc1)
// EPI 3: out f32  = v + f32 residual         (fc2 + residual -> final out)
template <int EPI>
__global__ __launch_bounds__(256) void gemm_kernel(const unsigned short* __restrict__ A,
                                                   const unsigned short* __restrict__ Bt,
                                                   const float* __restrict__ bias,
                                                   const float* __restrict__ res,
                                                   void* __restrict__ out, int K, int N) {
  __shared__ __align__(16) unsigned short As[64 * 32];
  __shared__ __align__(16) unsigned short Bs[64 * 32];
  const int tid = threadIdx.x;
  const int wave = tid >> 6;
  const int lane = tid & 63;
  const int quad = lane >> 4;
  const int l16 = lane & 15;
  const long m0 = (long)blockIdx.y * 64;
  const long n0 = (long)blockIdx.x * 64;

  const int sr = tid >> 2;        // 0..63 row of staged tile
  const int sk = (tid & 3) * 8;   // 0,8,16,24 k-offset
  const unsigned short* Ap = A + (m0 + sr) * K + sk;
  const unsigned short* Bp = Bt + (n0 + sr) * K + sk;

  f4 acc[4] = {};
  for (int k0 = 0; k0 < K; k0 += 32) {
    *(uint4*)&As[sr * 32 + sk] = *(const uint4*)(Ap + k0);
    *(uint4*)&Bs[sr * 32 + sk] = *(const uint4*)(Bp + k0);
    __syncthreads();
    bf8 a = *(const bf8*)&As[(wave * 16 + l16) * 32 + quad * 8];
#pragma unroll
    for (int nt = 0; nt < 4; nt++) {
      bf8 b = *(const bf8*)&Bs[(nt * 16 + l16) * 32 + quad * 8];
      acc[nt] = __builtin_amdgcn_mfma_f32_16x16x32_bf16(a, b, acc[nt], 0, 0, 0);
    }
    __syncthreads();
  }
#pragma unroll
  for (int nt = 0; nt < 4; nt++) {
    long n = n0 + nt * 16 + l16;
    float bv = bias[n];
#pragma unroll
    for (int r = 0; r < 4; r++) {
      long m = m0 + wave * 16 + quad * 4 + r;
      float v = acc[nt][r] + bv;
      long idx = m * N + n;
      if (EPI == 0) {
        ((unsigned short*)out)[idx] = f2b(v);
      } else if (EPI == 1) {
        ((float*)out)[idx] = v + res[idx];
      } else if (EPI == 2) {
        float gv = 0.5f * v * (1.0f + erff(v * 0.70710678118654752440f));
        ((unsigned short*)out)[idx] = f2b(gv);
      } else {
        ((float*)out)[idx] = v + res[idx];
      }
    }
  }
}

// ---------------- shifted-window attention, one block per (batch, window, head) ----------------
__global__ __launch_bounds__(256) void attn_kernel(const unsigned short* __restrict__ qkv,  // [B*3136,576] bf16
                                                   const float* __restrict__ rel_table,     // [169,6] f32
                                                   const int* __restrict__ rel_index,       // [49,49]
                                                   const float* __restrict__ mask,          // [64,49,49] f32
                                                   unsigned short* __restrict__ o) {        // [B*3136,192] bf16
  __shared__ float qs[49 * 33], ks[49 * 33], vs[49 * 33];
  __shared__ float S[49 * 50];
  __shared__ int tok[49];
  int blk = blockIdx.x;
  int head = blk % 6;
  int wi = (blk / 6) & 63;
  int b = blk / (6 * 64);
  int tid = threadIdx.x;
  if (tid < 49) {
    int r = tid / 7, c = tid - r * 7;
    // shifted-image coord -> original token: orig = (win_coord + 3) % 56
    int h = ((wi >> 3) * 7 + r + 3) % 56;
    int w = ((wi & 7) * 7 + c + 3) % 56;
    tok[tid] = (b * 56 + h) * 56 + w;
  }
  __syncthreads();
  const float scale = 0.17677669529663687f;  // 1/sqrt(32)
  for (int e = tid; e < 49 * 32; e += 256) {
    int n = e >> 5, d = e & 31;
    long base = (long)tok[n] * 576 + head * 32 + d;
    qs[n * 33 + d] = b2f(qkv[base]) * scale;
    ks[n * 33 + d] = b2f(qkv[base + 192]);
    vs[n * 33 + d] = b2f(qkv[base + 384]);
  }
  __syncthreads();
  {
    int wave = tid >> 6, lane = tid & 63;
    for (int i = wave; i < 49; i += 4) {
      if (lane < 49) {
        float s = 0.0f;
#pragma unroll
        for (int d = 0; d < 32; d++) s += qs[i * 33 + d] * ks[lane * 33 + d];
        s += rel_table[rel_index[i * 49 + lane] * 6 + head];
        s += mask[(wi * 49 + i) * 49 + lane];
        S[i * 50 + lane] = s;
      }
    }
  }
  __syncthreads();
  if (tid < 49) {
    float mx = -1e30f;
    for (int j = 0; j < 49; j++) mx = fmaxf(mx, S[tid * 50 + j]);
    float sum = 0.0f;
    for (int j = 0; j < 49; j++) {
      float e = __expf(S[tid * 50 + j] - mx);
      S[tid * 50 + j] = e;
      sum += e;
    }
    float inv = 1.0f / sum;
    for (int j = 0; j < 49; j++) S[tid * 50 + j] *= inv;
  }
  __syncthreads();
  for (int e = tid; e < 49 * 32; e += 256) {
    int i = e >> 5, d = e & 31;
    float s = 0.0f;
#pragma unroll
    for (int j = 0; j < 49; j++) s += S[i * 50 + j] * vs[j * 33 + d];
    o[(long)tok[i] * 192 + head * 32 + d] = f2b(s);
  }
}

extern "C" void kernel_launch(void* const* d_in, const int* in_sizes, int n_in,
                              void* d_out, int out_size, void* d_ws, size_t ws_size,
                              hipStream_t stream) {
  const float* x      = (const float*)d_in[0];
  const float* n1g    = (const float*)d_in[1];
  const float* n1b    = (const float*)d_in[2];
  const float* qkv_w  = (const float*)d_in[3];
  const float* qkv_b  = (const float*)d_in[4];
  const float* proj_w = (const float*)d_in[5];
  const float* proj_b = (const float*)d_in[6];
  const float* n2g    = (const float*)d_in[7];
  const float* n2b    = (const float*)d_in[8];
  const float* fc1_w  = (const float*)d_in[9];
  const float* fc1_b  = (const float*)d_in[10];
  const float* fc2_w  = (const float*)d_in[11];
  const float* fc2_b  = (const float*)d_in[12];
  const float* rel_t  = (const float*)d_in[13];
  const int*   rel_i  = (const int*)d_in[14];
  const float* mask   = (const float*)d_in[15];

  char* ws = (char*)d_ws;
  unsigned short* qkv_wT  = (unsigned short*)(ws + 0);          // 576x192 bf16
  unsigned short* proj_wT = (unsigned short*)(ws + 221184);     // 192x192
  unsigned short* fc1_wT  = (unsigned short*)(ws + 294912);     // 768x192
  unsigned short* fc2_wT  = (unsigned short*)(ws + 589824);     // 192x768
  unsigned short* bufA    = (unsigned short*)(ws + 884736);     // 100352x192 bf16 (xn / o / xn2)
  unsigned short* bufB    = (unsigned short*)(ws + 39419904ULL);// 100352x576/768 bf16 (qkv then y1)
  float*          xres    = (float*)(ws + 193560576ULL);        // 100352x192 f32

  const int M = 100352;  // 32 * 56 * 56

  transpose_kernel<<<(192 * 576 + 255) / 256, 256, 0, stream>>>(qkv_w, qkv_wT, 192, 576);
  transpose_kernel<<<(192 * 192 + 255) / 256, 256, 0, stream>>>(proj_w, proj_wT, 192, 192);
  transpose_kernel<<<(192 * 768 + 255) / 256, 256, 0, stream>>>(fc1_w, fc1_wT, 192, 768);
  transpose_kernel<<<(768 * 192 + 255) / 256, 256, 0, stream>>>(fc2_w, fc2_wT, 768, 192);

  ln_kernel<<<M / 4, 256, 0, stream>>>(x, n1g, n1b, bufA);
  gemm_kernel<0><<<dim3(576 / 64, M / 64), 256, 0, stream>>>(bufA, qkv_wT, qkv_b, nullptr, bufB, 192, 576);
  attn_kernel<<<32 * 64 * 6, 256, 0, stream>>>(bufB, rel_t, rel_i, mask, bufA);
  gemm_kernel<1><<<dim3(192 / 64, M / 64), 256, 0, stream>>>(bufA, proj_wT, proj_b, x, xres, 192, 192);
  ln_kernel<<<M / 4, 256, 0, stream>>>(xres, n2g, n2b, bufA);
  gemm_kernel<2><<<dim3(768 / 64, M / 64), 256, 0, stream>>>(bufA, fc1_wT, fc1_b, nullptr, bufB, 192, 768);
  gemm_kernel<3><<<dim3(192 / 64, M / 64), 256, 0, stream>>>(bufB, fc2_wT, fc2_b, xres, d_out, 768, 192);
}

// Round 5
// 596.683 us; speedup vs baseline: 1.2376x; 1.2376x over previous
//
#include <hip/hip_runtime.h>

typedef __bf16 bf8 __attribute__((ext_vector_type(8)));
typedef float f4 __attribute__((ext_vector_type(4)));

__device__ __forceinline__ float b2f(unsigned short u) {
  union { unsigned int i; float f; } c; c.i = ((unsigned int)u) << 16; return c.f;
}
__device__ __forceinline__ unsigned short f2b(float f) {
  union { float f; unsigned int i; } c; c.f = f;
  unsigned int i = c.i;
  return (unsigned short)((i + 0x7FFFu + ((i >> 16) & 1u)) >> 16);  // RNE
}

// ---------------- weight transpose+cast: f32 [K,N] -> bf16 [N,K] ----------------
__global__ void transpose_kernel(const float* __restrict__ in,
                                 unsigned short* __restrict__ out, int K, int N) {
  int idx = blockIdx.x * 256 + threadIdx.x;
  if (idx < K * N) {
    int n = idx / K, k = idx - n * K;
    out[idx] = f2b(in[k * N + n]);
  }
}

// ---------------- LayerNorm: C=192, one wave per token, f32 in -> bf16 out ----------------
__global__ __launch_bounds__(256) void ln_kernel(const float* __restrict__ xin,
                                                 const float* __restrict__ g,
                                                 const float* __restrict__ bb,
                                                 unsigned short* __restrict__ out) {
  long token = (long)blockIdx.x * 4 + (threadIdx.x >> 6);
  int lane = threadIdx.x & 63;
  const float* row = xin + token * 192;
  float v[3] = {row[lane], row[lane + 64], row[lane + 128]};
  float s = v[0] + v[1] + v[2];
#pragma unroll
  for (int m = 1; m < 64; m <<= 1) s += __shfl_xor(s, m, 64);
  float mean = s * (1.0f / 192.0f);
  float d0 = v[0] - mean, d1 = v[1] - mean, d2 = v[2] - mean;
  float dd = d0 * d0 + d1 * d1 + d2 * d2;
#pragma unroll
  for (int m = 1; m < 64; m <<= 1) dd += __shfl_xor(dd, m, 64);
  float rstd = rsqrtf(dd * (1.0f / 192.0f) + 1e-5f);
  unsigned short* orow = out + token * 192;
#pragma unroll
  for (int i = 0; i < 3; i++) {
    int c = lane + i * 64;
    orow[c] = f2b((v[i] - mean) * rstd * g[c] + bb[c]);
  }
}

// ---------------- MFMA GEMM: out = A[M,K](bf16) @ Bt[N,K]^T(bf16) + bias(f32) ----------------
template <int EPI>
__global__ __launch_bounds__(256) void gemm_kernel(const unsigned short* __restrict__ A,
                                                   const unsigned short* __restrict__ Bt,
                                                   const float* __restrict__ bias,
                                                   const float* __restrict__ res,
                                                   void* __restrict__ out, int K, int N) {
  __shared__ __align__(16) unsigned short As[64 * 32];
  __shared__ __align__(16) unsigned short Bs[64 * 32];
  const int tid = threadIdx.x;
  const int wave = tid >> 6;
  const int lane = tid & 63;
  const int quad = lane >> 4;
  const int l16 = lane & 15;
  const long m0 = (long)blockIdx.y * 64;
  const long n0 = (long)blockIdx.x * 64;

  const int sr = tid >> 2;
  const int sk = (tid & 3) * 8;
  const unsigned short* Ap = A + (m0 + sr) * K + sk;
  const unsigned short* Bp = Bt + (n0 + sr) * K + sk;

  f4 acc[4] = {};
  for (int k0 = 0; k0 < K; k0 += 32) {
    *(uint4*)&As[sr * 32 + sk] = *(const uint4*)(Ap + k0);
    *(uint4*)&Bs[sr * 32 + sk] = *(const uint4*)(Bp + k0);
    __syncthreads();
    bf8 a = *(const bf8*)&As[(wave * 16 + l16) * 32 + quad * 8];
#pragma unroll
    for (int nt = 0; nt < 4; nt++) {
      bf8 b = *(const bf8*)&Bs[(nt * 16 + l16) * 32 + quad * 8];
      acc[nt] = __builtin_amdgcn_mfma_f32_16x16x32_bf16(a, b, acc[nt], 0, 0, 0);
    }
    __syncthreads();
  }
#pragma unroll
  for (int nt = 0; nt < 4; nt++) {
    long n = n0 + nt * 16 + l16;
    float bv = bias[n];
#pragma unroll
    for (int r = 0; r < 4; r++) {
      long m = m0 + wave * 16 + quad * 4 + r;
      float v = acc[nt][r] + bv;
      long idx = m * N + n;
      if (EPI == 0) {
        ((unsigned short*)out)[idx] = f2b(v);
      } else if (EPI == 1) {
        ((float*)out)[idx] = v + res[idx];
      } else if (EPI == 2) {
        float gv = 0.5f * v * (1.0f + erff(v * 0.70710678118654752440f));
        ((unsigned short*)out)[idx] = f2b(gv);
      } else {
        ((float*)out)[idx] = v + res[idx];
      }
    }
  }
}

// ---------------- MFMA shifted-window attention (self-contained, no bm buffer) ----------------
// Block = 128 threads = 2 waves; each wave owns one (b, wi, head).
// Per-wave LDS (shorts): Q[64x40]@0, K[64x40]@2560, Vt[32x72]@5120, P[64x72]@7424, total 12032.
// All LDS consumed by MFMA is fully initialized (Q/K rows 49..63 zeroed, Vt cols 48..63 zeroed).
__global__ __launch_bounds__(128) void attn_kernel(const unsigned short* __restrict__ qkv,  // [B*3136,576] bf16
                                                   const float* __restrict__ rel_t,         // [169,6] f32
                                                   unsigned short* __restrict__ o) {        // [B*3136,192] bf16
  __shared__ __align__(16) unsigned short sh[2 * 12032];
  __shared__ float relh[2][170];
  __shared__ int toksh[2][49];
  __shared__ int zsh[2][49];
  const int wave = threadIdx.x >> 6;
  const int lane = threadIdx.x & 63;
  const int quad = lane >> 4;
  const int l16 = lane & 15;
  const int p = blockIdx.x * 2 + wave;  // 0..12287
  const int head = p % 6;
  const int wib = p / 6;
  const int wi = wib & 63;
  const int b = wib >> 6;
  unsigned short* Qs = sh + wave * 12032;   // stride 40
  unsigned short* Ks = Qs + 2560;           // stride 40
  unsigned short* Vts = Qs + 5120;          // stride 72 (32 dims x 64 tokens)
  unsigned short* Ps = Qs + 7424;           // stride 72

  // token map + zone codes (zones in SHIFTED-frame position, per Swin img_mask construction)
  if (lane < 49) {
    int r = lane / 7, c = lane - (lane / 7) * 7;
    int ph = (wi >> 3) * 7 + r, pw = (wi & 7) * 7 + c;
    int h = ph + 3; if (h >= 56) h -= 56;
    int w = pw + 3; if (w >= 56) w -= 56;
    toksh[wave][lane] = (b * 56 + h) * 56 + w;
    int zh = (ph < 49) ? 0 : (ph < 53 ? 1 : 2);
    int zw = (pw < 49) ? 0 : (pw < 53 ? 1 : 2);
    zsh[wave][lane] = zh * 3 + zw;
  }
  // rel_table column for this head -> LDS (169 floats)
  for (int i = lane; i < 169; i += 64) relh[wave][i] = rel_t[i * 6 + head];
  // zero Q,K rows 49..63 (600 shorts = 300 uints each) and Vt token-cols 48..63
  {
    unsigned int* qz = (unsigned int*)(Qs + 49 * 40);
    unsigned int* kz = (unsigned int*)(Ks + 49 * 40);
    for (int i = lane; i < 300; i += 64) { qz[i] = 0u; kz[i] = 0u; }
#pragma unroll
    for (int e = 0; e < 4; e++) {
      int ee = lane + e * 64;  // 0..255
      int d = ee >> 3, c8 = ee & 7;
      *(unsigned int*)&Vts[d * 72 + 48 + c8 * 2] = 0u;  // max 31*72+62=2294 < 2304
    }
  }
  __syncthreads();

  // stage Q, K, Vt (49 tokens x 32 dims, 16B chunks)
  for (int e = lane; e < 196; e += 64) {
    int n = e >> 2, c = e & 3;
    int t = toksh[wave][n];
    const uint4* src = (const uint4*)(qkv + (long)t * 576 + head * 32);
    uint4 qc = src[c];
    uint4 kc = src[c + 24];
    uint4 vc = src[c + 48];
    *(uint4*)&Qs[n * 40 + c * 8] = qc;
    *(uint4*)&Ks[n * 40 + c * 8] = kc;
    const unsigned short* vv = (const unsigned short*)&vc;
#pragma unroll
    for (int j = 0; j < 8; j++) Vts[(c * 8 + j) * 72 + n] = vv[j];
  }
  __syncthreads();

  // S = Q @ K^T  (16 MFMAs, K=32 exact)
  bf8 af[4], bf_[4];
#pragma unroll
  for (int i = 0; i < 4; i++) af[i] = *(const bf8*)&Qs[(16 * i + l16) * 40 + quad * 8];
#pragma unroll
  for (int j = 0; j < 4; j++) bf_[j] = *(const bf8*)&Ks[(16 * j + l16) * 40 + quad * 8];
  f4 S[4][4];
#pragma unroll
  for (int i = 0; i < 4; i++)
#pragma unroll
    for (int j = 0; j < 4; j++)
      S[i][j] = __builtin_amdgcn_mfma_f32_16x16x32_bf16(af[i], bf_[j], (f4){0.f, 0.f, 0.f, 0.f}, 0, 0, 0);

  // per-lane column attributes
  int colv[4], colkey[4], zcol[4];
#pragma unroll
  for (int jt = 0; jt < 4; jt++) {
    int col = 16 * jt + l16;
    int cc = col < 49 ? col : 48;
    int rj = cc / 7, cj = cc - rj * 7;
    colkey[jt] = rj * 13 + cj;
    zcol[jt] = zsh[wave][cc];
    colv[jt] = (col < 49);
  }

  // scale + analytic bias/mask + in-register softmax -> P (bf16) in LDS
  const float sc = 0.17677669529663687f;  // 1/sqrt(32)
#pragma unroll
  for (int it = 0; it < 4; it++) {
#pragma unroll
    for (int r = 0; r < 4; r++) {
      int row = 16 * it + quad * 4 + r;
      int row2 = row < 49 ? row : 48;
      int ri = row2 / 7, ci = row2 - ri * 7;
      int rk = ri * 13 + ci + 84;
      int zr = zsh[wave][row2];
      float v[4];
#pragma unroll
      for (int jt = 0; jt < 4; jt++) {
        float bias = relh[wave][rk - colkey[jt]];
        float msk = (zr == zcol[jt]) ? 0.0f : -100.0f;
        float val = S[it][jt][r] * sc + bias + msk;
        v[jt] = colv[jt] ? val : -1e30f;
      }
      float mx = fmaxf(fmaxf(v[0], v[1]), fmaxf(v[2], v[3]));
#pragma unroll
      for (int m = 1; m < 16; m <<= 1) mx = fmaxf(mx, __shfl_xor(mx, m, 64));
      float e0 = __expf(v[0] - mx), e1 = __expf(v[1] - mx), e2 = __expf(v[2] - mx), e3 = __expf(v[3] - mx);
      float sum = e0 + e1 + e2 + e3;
#pragma unroll
      for (int m = 1; m < 16; m <<= 1) sum += __shfl_xor(sum, m, 64);
      float inv = 1.0f / sum;
      Ps[row * 72 + 0 + l16] = f2b(e0 * inv);
      Ps[row * 72 + 16 + l16] = f2b(e1 * inv);
      Ps[row * 72 + 32 + l16] = f2b(e2 * inv);
      Ps[row * 72 + 48 + l16] = f2b(e3 * inv);
    }
  }
  __syncthreads();

  // O = P @ V   (P: 64x64 A-operand, Vt: V^T as B-operand, 16 MFMAs)
  f4 O[4][2] = {};
#pragma unroll
  for (int ks = 0; ks < 2; ks++) {
    bf8 pv[2];
#pragma unroll
    for (int nt = 0; nt < 2; nt++) pv[nt] = *(const bf8*)&Vts[(16 * nt + l16) * 72 + ks * 32 + quad * 8];
#pragma unroll
    for (int mt = 0; mt < 4; mt++) {
      bf8 pa = *(const bf8*)&Ps[(16 * mt + l16) * 72 + ks * 32 + quad * 8];
#pragma unroll
      for (int nt = 0; nt < 2; nt++)
        O[mt][nt] = __builtin_amdgcn_mfma_f32_16x16x32_bf16(pa, pv[nt], O[mt][nt], 0, 0, 0);
    }
  }
  // store
#pragma unroll
  for (int mt = 0; mt < 4; mt++) {
#pragma unroll
    for (int r = 0; r < 4; r++) {
      int row = 16 * mt + quad * 4 + r;
      if (row < 49) {
        long base = (long)toksh[wave][row] * 192 + head * 32 + l16;
        o[base] = f2b(O[mt][0][r]);
        o[base + 16] = f2b(O[mt][1][r]);
      }
    }
  }
}

extern "C" void kernel_launch(void* const* d_in, const int* in_sizes, int n_in,
                              void* d_out, int out_size, void* d_ws, size_t ws_size,
                              hipStream_t stream) {
  const float* x      = (const float*)d_in[0];
  const float* n1g    = (const float*)d_in[1];
  const float* n1b    = (const float*)d_in[2];
  const float* qkv_w  = (const float*)d_in[3];
  const float* qkv_b  = (const float*)d_in[4];
  const float* proj_w = (const float*)d_in[5];
  const float* proj_b = (const float*)d_in[6];
  const float* n2g    = (const float*)d_in[7];
  const float* n2b    = (const float*)d_in[8];
  const float* fc1_w  = (const float*)d_in[9];
  const float* fc1_b  = (const float*)d_in[10];
  const float* fc2_w  = (const float*)d_in[11];
  const float* fc2_b  = (const float*)d_in[12];
  const float* rel_t  = (const float*)d_in[13];
  const float* mask   = (const float*)d_in[15];
  (void)mask;

  char* ws = (char*)d_ws;
  unsigned short* qkv_wT  = (unsigned short*)(ws + 0);          // 576x192 bf16
  unsigned short* proj_wT = (unsigned short*)(ws + 221184);     // 192x192
  unsigned short* fc1_wT  = (unsigned short*)(ws + 294912);     // 768x192
  unsigned short* fc2_wT  = (unsigned short*)(ws + 589824);     // 192x768
  unsigned short* bufA    = (unsigned short*)(ws + 884736);     // 100352x192 bf16
  unsigned short* bufB    = (unsigned short*)(ws + 39419904ULL);// 100352x576/768 bf16
  float*          xres    = (float*)(ws + 193560576ULL);        // 100352x192 f32

  const int M = 100352;  // 32 * 56 * 56

  transpose_kernel<<<(192 * 576 + 255) / 256, 256, 0, stream>>>(qkv_w, qkv_wT, 192, 576);
  transpose_kernel<<<(192 * 192 + 255) / 256, 256, 0, stream>>>(proj_w, proj_wT, 192, 192);
  transpose_kernel<<<(192 * 768 + 255) / 256, 256, 0, stream>>>(fc1_w, fc1_wT, 192, 768);
  transpose_kernel<<<(768 * 192 + 255) / 256, 256, 0, stream>>>(fc2_w, fc2_wT, 768, 192);

  ln_kernel<<<M / 4, 256, 0, stream>>>(x, n1g, n1b, bufA);
  gemm_kernel<0><<<dim3(576 / 64, M / 64), 256, 0, stream>>>(bufA, qkv_wT, qkv_b, nullptr, bufB, 192, 576);
  attn_kernel<<<12288 / 2, 128, 0, stream>>>(bufB, rel_t, bufA);
  gemm_kernel<1><<<dim3(192 / 64, M / 64), 256, 0, stream>>>(bufA, proj_wT, proj_b, x, xres, 192, 192);
  ln_kernel<<<M / 4, 256, 0, stream>>>(xres, n2g, n2b, bufA);
  gemm_kernel<2><<<dim3(768 / 64, M / 64), 256, 0, stream>>>(bufA, fc1_wT, fc1_b, nullptr, bufB, 192, 768);
  gemm_kernel<3><<<dim3(192 / 64, M / 64), 256, 0, stream>>>(bufB, fc2_wT, fc2_b, xres, d_out, 768, 192);
}